// Round 11
// baseline (185.610 us; speedup 1.0000x reference)
//
#include <hip/hip_runtime.h>

// ---------------------------------------------------------------------------
// MultiHeadSelfAttention: GroupNorm(8,256) -> qkv 1x1 -> 8-head attn (N=4096,
// hd=32) -> proj 1x1.  B=2, C=256, H=W=64.
//   - GEMMs: plain fp16 MFMA (W pre-cast in prep kernel).
//   - Attention v6 (best measured): dual-Q waves, 64-key frag-order LDS
//     tiles (0 conflicts), S^T operand-swap keeps P in registers, K=32 PV
//     via permuted K staging, 100% occupancy.  Split-K x8 across TWO
//     dispatches (4 parts each) so non-attn kernels surface in top-5.
//   - O' partials fp16 (V pre-scaled 2^-10), l fp32, 8-part combine.
// ---------------------------------------------------------------------------

typedef _Float16 half8 __attribute__((ext_vector_type(8)));
typedef __fp16   fp16x2 __attribute__((ext_vector_type(2)));  // pkrtz return type
typedef float    f32x4 __attribute__((ext_vector_type(4)));
typedef int      int2v __attribute__((ext_vector_type(2)));
typedef int      int4v __attribute__((ext_vector_type(4)));

__device__ __forceinline__ f32x4 mfma16(half8 a, half8 b, f32x4 c) {
  return __builtin_amdgcn_mfma_f32_16x16x32_f16(a, b, c, 0, 0, 0);
}

#if __has_builtin(__builtin_amdgcn_exp2f)
#define EXP2(x) __builtin_amdgcn_exp2f(x)
#else
#define EXP2(x) exp2f(x)
#endif

__device__ __forceinline__ unsigned short h_bits(_Float16 h) {
  return __builtin_bit_cast(unsigned short, h);
}
__device__ __forceinline__ int h2_bits(fp16x2 h) {
  return __builtin_bit_cast(int, h);
}

constexpr float CSCALE = (float)(1.4426950408889634 / 5.656854249492381); // log2(e)/sqrt(32)
constexpr float VSCALE = 0.0009765625f;   // 2^-10: bounds unnormalized O for fp16
constexpr float VUNSC  = 1024.0f;

// ---------------------------------------------------------------------------
// 1) prep: GroupNorm stats (blocks 0..511) + weight cast (blocks 512..1535).
// ---------------------------------------------------------------------------
__global__ __launch_bounds__(256) void prep(const float* __restrict__ x,
                                            float* __restrict__ stats,
                                            const float* __restrict__ wq,
                                            const float* __restrict__ wp,
                                            _Float16* __restrict__ wqh,
                                            _Float16* __restrict__ wph) {
  const int tid = threadIdx.x;
  if (blockIdx.x < 512) {
    const int bg = blockIdx.x >> 5, ch = blockIdx.x & 31;
    const float* p = x + (size_t)bg * 131072 + (size_t)ch * 4096;
    float s = 0.f, ss = 0.f;
#pragma unroll
    for (int j = 0; j < 4; ++j) {
      f32x4 v = *(const f32x4*)(p + j * 1024 + tid * 4);
#pragma unroll
      for (int k = 0; k < 4; ++k) { s += v[k]; ss += v[k] * v[k]; }
    }
#pragma unroll
    for (int m = 1; m <= 32; m <<= 1) { s += __shfl_xor(s, m); ss += __shfl_xor(ss, m); }
    __shared__ float red[8];
    const int wv = tid >> 6;
    if ((tid & 63) == 0) { red[wv * 2] = s; red[wv * 2 + 1] = ss; }
    __syncthreads();
    if (tid == 0) {
      float S = red[0] + red[2] + red[4] + red[6];
      float SS = red[1] + red[3] + red[5] + red[7];
      atomicAdd(&stats[bg * 2], S);
      atomicAdd(&stats[bg * 2 + 1], SS);
    }
  } else {
    const int idx = (blockIdx.x - 512) * 256 + tid;
    if (idx < 196608) {
      wqh[idx] = (_Float16)wq[idx];
    } else {
      wph[idx - 196608] = (_Float16)wp[idx - 196608];
    }
  }
}

// ---------------------------------------------------------------------------
// 2) GroupNorm apply + transpose: x[b][c][n] -> hn[b][n][c] (fp16).
// ---------------------------------------------------------------------------
__global__ __launch_bounds__(256) void gn_apply(const float* __restrict__ x,
                                                const float* __restrict__ gw,
                                                const float* __restrict__ gb,
                                                const float* __restrict__ stats,
                                                _Float16* __restrict__ hn) {
  __shared__ float tile[64 * 65];
  const int tid = threadIdx.x;
  const int a = tid & 15;
  const int row16 = tid >> 4;
  const int b = blockIdx.z, c0 = blockIdx.y * 64, n0 = blockIdx.x * 64;
#pragma unroll
  for (int m = 0; m < 4; ++m) {
    const int cl = row16 + 16 * m;
    const int c = c0 + cl;
    const int g = c >> 5;
    const float s = stats[(b * 8 + g) * 2];
    const float ss = stats[(b * 8 + g) * 2 + 1];
    const float mean = s * (1.f / 131072.f);
    const float var = ss * (1.f / 131072.f) - mean * mean;
    const float rstd = rsqrtf(var + 1e-5f);
    const float ga = gw[c] * rstd;
    const float be = gb[c] - mean * ga;
    f32x4 xv = *(const f32x4*)(x + ((size_t)(b * 256 + c)) * 4096 + n0 + a * 4);
#pragma unroll
    for (int j = 0; j < 4; ++j) tile[cl * 65 + a * 4 + j] = xv[j] * ga + be;
  }
  __syncthreads();
#pragma unroll
  for (int m = 0; m < 4; ++m) {
    const int nl = row16 + 16 * m;
    const int cb = a * 4;
    int2v uh;
    unsigned short hh[4];
#pragma unroll
    for (int j = 0; j < 4; ++j) {
      hh[j] = h_bits((_Float16)tile[(cb + j) * 65 + nl]);
    }
    uh[0] = hh[0] | (hh[1] << 16); uh[1] = hh[2] | (hh[3] << 16);
    size_t off = ((size_t)(b * 4096 + n0 + nl)) * 256 + c0 + cb;
    *(int2v*)(hn + off) = uh;
  }
}

// ---------------------------------------------------------------------------
// 3) fp16 GEMM: out[M][4096] = W[M][256] @ Bm^T  (Bm is [b][n][256] fp16).
//    64x64 tile, BK=64, frag-order LDS, register-prefetch 1-barrier K-loop.
//    MODE 0 (QKV, M=768): q*CSCALE,k -> qkT[b][n][512]; v*2^-10 -> v_t.
//    MODE 1 (proj, M=256): fp32 out[b][c][n] + bias.
// ---------------------------------------------------------------------------
template <int MODE>
__global__ __launch_bounds__(256) void gemm_f16(
    const _Float16* __restrict__ W, const _Float16* __restrict__ Bm,
    const float* __restrict__ bias,
    _Float16* __restrict__ qkT, _Float16* __restrict__ v_t,
    float* __restrict__ outp) {
  __shared__ _Float16 a_lds[2][4096];
  __shared__ _Float16 b_lds[2][4096];
  const int tid = threadIdx.x, lane = tid & 63, wv = tid >> 6;
  const int qq = lane >> 4, ii = lane & 15;
  const int m0 = blockIdx.x * 64, n0 = blockIdx.y * 64, bz = blockIdx.z;

  const _Float16* asrc[2];
  const _Float16* bsrc[2];
  int dst8[2];
#pragma unroll
  for (int rep = 0; rep < 2; ++rep) {
    const int idx = tid + 256 * rep;
    dst8[rep] = idx * 8;
    const int j = idx >> 7, c = (idx >> 6) & 1, l = idx & 63;
    const int lq = l >> 4, li = l & 15;
    asrc[rep] = W + (size_t)(m0 + 16 * j + li) * 256 + 32 * c + 8 * lq;
    bsrc[rep] = Bm + ((size_t)(bz * 4096 + n0 + 16 * j + li)) * 256 + 32 * c + 8 * lq;
  }

  f32x4 acc[4] = {};

  half8 ar0 = *(const half8*)asrc[0];
  half8 ar1 = *(const half8*)asrc[1];
  half8 br0 = *(const half8*)bsrc[0];
  half8 br1 = *(const half8*)bsrc[1];
  *(half8*)(a_lds[0] + dst8[0]) = ar0;
  *(half8*)(a_lds[0] + dst8[1]) = ar1;
  *(half8*)(b_lds[0] + dst8[0]) = br0;
  *(half8*)(b_lds[0] + dst8[1]) = br1;
  __syncthreads();

  for (int it = 0; it < 4; ++it) {
    const int cur = it & 1;
    if (it < 3) {
      const int ko = (it + 1) * 64;
      ar0 = *(const half8*)(asrc[0] + ko);
      ar1 = *(const half8*)(asrc[1] + ko);
      br0 = *(const half8*)(bsrc[0] + ko);
      br1 = *(const half8*)(bsrc[1] + ko);
    }
    half8 ah0 = *(const half8*)(a_lds[cur] + ((wv * 2 + 0) * 64 + lane) * 8);
    half8 ah1 = *(const half8*)(a_lds[cur] + ((wv * 2 + 1) * 64 + lane) * 8);
#pragma unroll
    for (int t = 0; t < 4; ++t) {
      half8 b0 = *(const half8*)(b_lds[cur] + ((t * 2 + 0) * 64 + lane) * 8);
      half8 b1 = *(const half8*)(b_lds[cur] + ((t * 2 + 1) * 64 + lane) * 8);
      acc[t] = mfma16(ah0, b0, acc[t]);
      acc[t] = mfma16(ah1, b1, acc[t]);
    }
    if (it < 3) {
      _Float16* an = a_lds[cur ^ 1];
      _Float16* bn = b_lds[cur ^ 1];
      *(half8*)(an + dst8[0]) = ar0;
      *(half8*)(an + dst8[1]) = ar1;
      *(half8*)(bn + dst8[0]) = br0;
      *(half8*)(bn + dst8[1]) = br1;
    }
    __syncthreads();
  }

  const int och0 = m0 + 16 * wv + 4 * qq;
  if (MODE == 0) {
    if (m0 < 512) {
      const float sc = (m0 < 256) ? CSCALE : 1.0f;
#pragma unroll
      for (int t = 0; t < 4; ++t) {
        const int n = n0 + 16 * t + ii;
        unsigned short hh[4];
#pragma unroll
        for (int r = 0; r < 4; ++r) {
          hh[r] = h_bits((_Float16)((acc[t][r] + bias[och0 + r]) * sc));
        }
        int2v u;
        u[0] = hh[0] | (hh[1] << 16);
        u[1] = hh[2] | (hh[3] << 16);
        *(int2v*)(qkT + ((size_t)(bz * 4096 + n)) * 512 + och0) = u;
      }
    } else {
#pragma unroll
      for (int t = 0; t < 4; ++t) {
#pragma unroll
        for (int r = 0; r < 4; ++r) {
          const int och = och0 + r;
          const int d = och - 512;
          const int hd_ = d & 31, head = d >> 5;
          const int n = n0 + 16 * t + ii;
          v_t[((size_t)((bz * 8 + head) * 32 + hd_)) * 4096 + n] =
              (_Float16)((acc[t][r] + bias[och]) * VSCALE);
        }
      }
    }
  } else {
#pragma unroll
    for (int t = 0; t < 4; ++t) {
#pragma unroll
      for (int r = 0; r < 4; ++r) {
        const int och = och0 + r;
        const int n = n0 + 16 * t + ii;
        outp[((size_t)(bz * 256 + och)) * 4096 + n] = acc[t][r] + bias[och];
      }
    }
  }
}

// ---------------------------------------------------------------------------
// 4) Flash attention v6 (dual-Q, 64-key tiles, 100% occupancy).  One dispatch
//    covers 4 split-K parts of 512 keys (8 iters); pbase selects parts 0-3 /
//    4-7.  Grid (32,16,4) = 2048 blocks = 8 blocks/CU.
// ---------------------------------------------------------------------------
__global__ __launch_bounds__(256, 8) void attn_kernel(
    const _Float16* __restrict__ qkT, const _Float16* __restrict__ v_t,
    _Float16* __restrict__ opart, float* __restrict__ lpart, int pbase) {
  __shared__ _Float16 k_lds[2][2048];
  __shared__ _Float16 v_lds[2][2048];
  const int tid = threadIdx.x, lane = tid & 63, wv = tid >> 6;
  const int qq = lane >> 4, ii = lane & 15;
  const int bh = blockIdx.y, b = bh >> 3, h = bh & 7;
  const int n0 = blockIdx.x * 128;
  const int part = pbase + blockIdx.z;
  const int key0 = part * 512;

  // dual Q fragments (B-operand): q = n0+32wv+ii and +16.
  const _Float16* qbase =
      qkT + ((size_t)(b * 4096 + n0 + 32 * wv + ii)) * 512 + h * 32 + 8 * qq;
  half8 qf0 = *(const half8*)qbase;
  half8 qf1 = *(const half8*)(qbase + (size_t)16 * 512);

  // staging: thread tid stages half8 #tid of each matrix (frag-order dst).
  const int f = tid >> 6, l = tid & 63;
  const int fq = l >> 4, fi = l & 15;
  const int u0 = f >> 1, hf = f & 1;
  const int g = 32 * u0 + 4 * hf + 8 * (fi >> 2) + (fi & 3);  // permuted key
  const _Float16* ksrc =
      qkT + ((size_t)(b * 4096 + key0 + g)) * 512 + 256 + h * 32 + 8 * fq;
  const _Float16* vsrc =
      v_t + ((size_t)(bh * 32 + 16 * hf + fi)) * 4096 + key0 + 32 * u0 + 8 * fq;
  const int dst8 = tid * 8;

  half8 ones8;
#pragma unroll
  for (int j = 0; j < 8; ++j) ones8[j] = (_Float16)1.0f;

  f32x4 o00 = {}, o10 = {}, o01 = {}, o11 = {}, accl0 = {}, accl1 = {};

  half8 kr = *(const half8*)ksrc;
  half8 vr = *(const half8*)vsrc;
  *(half8*)(k_lds[0] + dst8) = kr;
  *(half8*)(v_lds[0] + dst8) = vr;
  __syncthreads();

  for (int kb = 0; kb < 8; ++kb) {
    const int cur = kb & 1;
    if (kb < 7) {
      kr = *(const half8*)(ksrc + (size_t)(kb + 1) * 64 * 512);
      vr = *(const half8*)(vsrc + (size_t)(kb + 1) * 64);
    }
    const _Float16* kbase = k_lds[cur];
    const _Float16* vbase = v_lds[cur];

#pragma unroll
    for (int u = 0; u < 2; ++u) {
      half8 kfa = *(const half8*)(kbase + u * 1024 + lane * 8);
      half8 kfb = *(const half8*)(kbase + u * 1024 + 512 + lane * 8);
      f32x4 z = {};
      f32x4 sa0 = mfma16(kfa, qf0, z);
      f32x4 sb0 = mfma16(kfb, qf0, z);
      f32x4 sa1 = mfma16(kfa, qf1, z);
      f32x4 sb1 = mfma16(kfb, qf1, z);
      int4v p0, p1;
      p0[0] = h2_bits(__builtin_amdgcn_cvt_pkrtz(EXP2(sa0[0]), EXP2(sa0[1])));
      p0[1] = h2_bits(__builtin_amdgcn_cvt_pkrtz(EXP2(sa0[2]), EXP2(sa0[3])));
      p0[2] = h2_bits(__builtin_amdgcn_cvt_pkrtz(EXP2(sb0[0]), EXP2(sb0[1])));
      p0[3] = h2_bits(__builtin_amdgcn_cvt_pkrtz(EXP2(sb0[2]), EXP2(sb0[3])));
      p1[0] = h2_bits(__builtin_amdgcn_cvt_pkrtz(EXP2(sa1[0]), EXP2(sa1[1])));
      p1[1] = h2_bits(__builtin_amdgcn_cvt_pkrtz(EXP2(sa1[2]), EXP2(sa1[3])));
      p1[2] = h2_bits(__builtin_amdgcn_cvt_pkrtz(EXP2(sb1[0]), EXP2(sb1[1])));
      p1[3] = h2_bits(__builtin_amdgcn_cvt_pkrtz(EXP2(sb1[2]), EXP2(sb1[3])));
      half8 pt0 = __builtin_bit_cast(half8, p0);
      half8 pt1 = __builtin_bit_cast(half8, p1);
      half8 vf0 = *(const half8*)(vbase + u * 1024 + lane * 8);
      half8 vf1 = *(const half8*)(vbase + u * 1024 + 512 + lane * 8);
      o00 = mfma16(vf0, pt0, o00);
      o10 = mfma16(vf1, pt0, o10);
      accl0 = mfma16(ones8, pt0, accl0);
      o01 = mfma16(vf0, pt1, o01);
      o11 = mfma16(vf1, pt1, o11);
      accl1 = mfma16(ones8, pt1, accl1);
    }

    if (kb < 7) {
      *(half8*)(k_lds[cur ^ 1] + dst8) = kr;
      *(half8*)(v_lds[cur ^ 1] + dst8) = vr;
    }
    __syncthreads();
  }

  // epilogue: fp16 unnormalized O' partials (V pre-scaled 2^-10), fp32 l.
#pragma unroll
  for (int hfq = 0; hfq < 2; ++hfq) {
    const f32x4 oa = hfq ? o01 : o00;   // d = 4qq+r
    const f32x4 ob = hfq ? o11 : o10;   // d = 16+4qq+r
    const int q = n0 + 32 * wv + 16 * hfq + ii;
    _Float16* base =
        opart + ((size_t)((part * 2 + b) * 4096 + q)) * 256 + h * 32;
    unsigned short hh[4];
    int2v ua;
#pragma unroll
    for (int r = 0; r < 4; ++r) hh[r] = h_bits((_Float16)oa[r]);
    ua[0] = hh[0] | (hh[1] << 16); ua[1] = hh[2] | (hh[3] << 16);
    *(int2v*)(base + 4 * qq) = ua;
#pragma unroll
    for (int r = 0; r < 4; ++r) hh[r] = h_bits((_Float16)ob[r]);
    ua[0] = hh[0] | (hh[1] << 16); ua[1] = hh[2] | (hh[3] << 16);
    *(int2v*)(base + 16 + 4 * qq) = ua;
    if (qq == 0) {
      lpart[((size_t)((part * 2 + b) * 4096 + q)) * 8 + h] =
          hfq ? accl1[0] : accl0[0];
    }
  }
}

// ---------------------------------------------------------------------------
// 5) Combine 8 split-K partials: o = 2^10 * sum(O') / sum(l), emit fp16.
// ---------------------------------------------------------------------------
__global__ __launch_bounds__(256) void attn_combine(
    const _Float16* __restrict__ opart, const float* __restrict__ lpart,
    _Float16* __restrict__ o16) {
  const int c = threadIdx.x, hh = c >> 5;
#pragma unroll
  for (int k = 0; k < 4; ++k) {
    const int row = blockIdx.x * 4 + k;          // (b*4096+q)
    const int b = row >> 12, q = row & 4095;
    float O = 0.f, L = 0.f;
#pragma unroll
    for (int p = 0; p < 8; ++p) {
      O += (float)opart[((size_t)((p * 2 + b) * 4096 + q)) * 256 + c];
      L += lpart[((size_t)((p * 2 + b) * 4096 + q)) * 8 + hh];
    }
    o16[(size_t)row * 256 + c] = (_Float16)(O * (VUNSC / L));
  }
}

// ---------------------------------------------------------------------------
extern "C" void kernel_launch(void* const* d_in, const int* in_sizes, int n_in,
                              void* d_out, int out_size, void* d_ws, size_t ws_size,
                              hipStream_t stream) {
  const float* x     = (const float*)d_in[0];
  const float* gnw   = (const float*)d_in[1];
  const float* gnb   = (const float*)d_in[2];
  const float* wqkv  = (const float*)d_in[3];
  const float* bqkv  = (const float*)d_in[4];
  const float* wproj = (const float*)d_in[5];
  const float* bproj = (const float*)d_in[6];
  float* out = (float*)d_out;

  char* ws = (char*)d_ws;
  size_t off = 0;
  auto alloc = [&](size_t bytes) -> char* {
    char* p = ws + off;
    off += (bytes + 255) & ~(size_t)255;
    return p;
  };
  float*    stats  = (float*)alloc(128);
  _Float16* hn     = (_Float16*)alloc((size_t)2 * 4096 * 256 * 2);
  _Float16* wq_h   = (_Float16*)alloc((size_t)768 * 256 * 2);
  _Float16* wp_h   = (_Float16*)alloc((size_t)256 * 256 * 2);
  _Float16* qkT    = (_Float16*)alloc((size_t)2 * 4096 * 512 * 2);
  _Float16* v_t    = (_Float16*)alloc((size_t)16 * 32 * 4096 * 2);
  _Float16* opart  = (_Float16*)alloc((size_t)16 * 4096 * 256 * 2);
  float*    lpart  = (float*)alloc((size_t)16 * 4096 * 8 * 4);
  _Float16* o16 = hn;  // hn dead after gemm<0>
  if (off > ws_size) return;

  (void)hipMemsetAsync(stats, 0, 256, stream);
  prep<<<1536, 256, 0, stream>>>(x, stats, wqkv, wproj, wq_h, wp_h);
  gn_apply<<<dim3(64, 4, 2), 256, 0, stream>>>(x, gnw, gnb, stats, hn);
  gemm_f16<0><<<dim3(12, 64, 2), 256, 0, stream>>>(wq_h, hn, bqkv, qkT, v_t,
                                                   nullptr);
  attn_kernel<<<dim3(32, 16, 4), 256, 0, stream>>>(qkT, v_t, opart, lpart, 0);
  attn_kernel<<<dim3(32, 16, 4), 256, 0, stream>>>(qkT, v_t, opart, lpart, 4);
  attn_combine<<<2048, 256, 0, stream>>>(opart, lpart, o16);
  gemm_f16<1><<<dim3(4, 64, 2), 256, 0, stream>>>(wp_h, o16, bproj, nullptr,
                                                  nullptr, out);
}

// Round 12
// 172.602 us; speedup vs baseline: 1.0754x; 1.0754x over previous
//
#include <hip/hip_runtime.h>

// ---------------------------------------------------------------------------
// MultiHeadSelfAttention: GroupNorm(8,256) -> qkv 1x1 -> 8-head attn (N=4096,
// hd=32) -> proj 1x1.  B=2, C=256, H=W=64.
//   - Harness poison of the 268 MB workspace costs a fixed ~47 us inside the
//     timed window (measured R11: fillBufferAligned 45 us) — not addressable.
//   - GEMMs: plain fp16 MFMA (W cast in prep; fp32-W staging regressed R9).
//   - Attention v6 (best measured 56.4 us): dual-Q waves, split-K x4, 64-key
//     frag-order LDS tiles (0 conflicts), S^T operand-swap keeps P in regs,
//     K=32 PV via permuted K staging, 100% occupancy.
//   - Softmax normalization folded into proj B-staging (per (q,h) scale) —
//     kills the combine kernel + o16 round-trip.  lsum is a tiny kernel.
// ---------------------------------------------------------------------------

typedef _Float16 half8 __attribute__((ext_vector_type(8)));
typedef __fp16   fp16x2 __attribute__((ext_vector_type(2)));  // pkrtz return type
typedef float    f32x4 __attribute__((ext_vector_type(4)));
typedef int      int2v __attribute__((ext_vector_type(2)));
typedef int      int4v __attribute__((ext_vector_type(4)));

__device__ __forceinline__ f32x4 mfma16(half8 a, half8 b, f32x4 c) {
  return __builtin_amdgcn_mfma_f32_16x16x32_f16(a, b, c, 0, 0, 0);
}

#if __has_builtin(__builtin_amdgcn_exp2f)
#define EXP2(x) __builtin_amdgcn_exp2f(x)
#else
#define EXP2(x) exp2f(x)
#endif

__device__ __forceinline__ unsigned short h_bits(_Float16 h) {
  return __builtin_bit_cast(unsigned short, h);
}
__device__ __forceinline__ int h2_bits(fp16x2 h) {
  return __builtin_bit_cast(int, h);
}

constexpr float CSCALE = (float)(1.4426950408889634 / 5.656854249492381); // log2(e)/sqrt(32)
constexpr float VSCALE = 0.0009765625f;   // 2^-10: bounds unnormalized O for fp16
constexpr float VUNSC  = 1024.0f;

// ---------------------------------------------------------------------------
// 1) prep: GroupNorm stats (blocks 0..511) + weight cast (blocks 512..1535).
// ---------------------------------------------------------------------------
__global__ __launch_bounds__(256) void prep(const float* __restrict__ x,
                                            float* __restrict__ stats,
                                            const float* __restrict__ wq,
                                            const float* __restrict__ wp,
                                            _Float16* __restrict__ wqh,
                                            _Float16* __restrict__ wph) {
  const int tid = threadIdx.x;
  if (blockIdx.x < 512) {
    const int bg = blockIdx.x >> 5, ch = blockIdx.x & 31;
    const float* p = x + (size_t)bg * 131072 + (size_t)ch * 4096;
    float s = 0.f, ss = 0.f;
#pragma unroll
    for (int j = 0; j < 4; ++j) {
      f32x4 v = *(const f32x4*)(p + j * 1024 + tid * 4);
#pragma unroll
      for (int k = 0; k < 4; ++k) { s += v[k]; ss += v[k] * v[k]; }
    }
#pragma unroll
    for (int m = 1; m <= 32; m <<= 1) { s += __shfl_xor(s, m); ss += __shfl_xor(ss, m); }
    __shared__ float red[8];
    const int wv = tid >> 6;
    if ((tid & 63) == 0) { red[wv * 2] = s; red[wv * 2 + 1] = ss; }
    __syncthreads();
    if (tid == 0) {
      float S = red[0] + red[2] + red[4] + red[6];
      float SS = red[1] + red[3] + red[5] + red[7];
      atomicAdd(&stats[bg * 2], S);
      atomicAdd(&stats[bg * 2 + 1], SS);
    }
  } else {
    const int idx = (blockIdx.x - 512) * 256 + tid;
    if (idx < 196608) {
      wqh[idx] = (_Float16)wq[idx];
    } else {
      wph[idx - 196608] = (_Float16)wp[idx - 196608];
    }
  }
}

// ---------------------------------------------------------------------------
// 2) GroupNorm apply + transpose: x[b][c][n] -> hn[b][n][c] (fp16).
// ---------------------------------------------------------------------------
__global__ __launch_bounds__(256) void gn_apply(const float* __restrict__ x,
                                                const float* __restrict__ gw,
                                                const float* __restrict__ gb,
                                                const float* __restrict__ stats,
                                                _Float16* __restrict__ hn) {
  __shared__ float tile[64 * 65];
  const int tid = threadIdx.x;
  const int a = tid & 15;
  const int row16 = tid >> 4;
  const int b = blockIdx.z, c0 = blockIdx.y * 64, n0 = blockIdx.x * 64;
#pragma unroll
  for (int m = 0; m < 4; ++m) {
    const int cl = row16 + 16 * m;
    const int c = c0 + cl;
    const int g = c >> 5;
    const float s = stats[(b * 8 + g) * 2];
    const float ss = stats[(b * 8 + g) * 2 + 1];
    const float mean = s * (1.f / 131072.f);
    const float var = ss * (1.f / 131072.f) - mean * mean;
    const float rstd = rsqrtf(var + 1e-5f);
    const float ga = gw[c] * rstd;
    const float be = gb[c] - mean * ga;
    f32x4 xv = *(const f32x4*)(x + ((size_t)(b * 256 + c)) * 4096 + n0 + a * 4);
#pragma unroll
    for (int j = 0; j < 4; ++j) tile[cl * 65 + a * 4 + j] = xv[j] * ga + be;
  }
  __syncthreads();
#pragma unroll
  for (int m = 0; m < 4; ++m) {
    const int nl = row16 + 16 * m;
    const int cb = a * 4;
    int2v uh;
    unsigned short hh[4];
#pragma unroll
    for (int j = 0; j < 4; ++j) {
      hh[j] = h_bits((_Float16)tile[(cb + j) * 65 + nl]);
    }
    uh[0] = hh[0] | (hh[1] << 16); uh[1] = hh[2] | (hh[3] << 16);
    size_t off = ((size_t)(b * 4096 + n0 + nl)) * 256 + c0 + cb;
    *(int2v*)(hn + off) = uh;
  }
}

// ---------------------------------------------------------------------------
// 3) QKV fp16 GEMM: 64x64 tile, BK=64, frag-order LDS, register-prefetch
//    1-barrier K-loop.  q*CSCALE,k -> qkT[b][n][512]; v*2^-10 -> v_t.
// ---------------------------------------------------------------------------
__global__ __launch_bounds__(256) void gemm_qkv(
    const _Float16* __restrict__ W, const _Float16* __restrict__ Bm,
    const float* __restrict__ bias,
    _Float16* __restrict__ qkT, _Float16* __restrict__ v_t) {
  __shared__ _Float16 a_lds[2][4096];
  __shared__ _Float16 b_lds[2][4096];
  const int tid = threadIdx.x, lane = tid & 63, wv = tid >> 6;
  const int qq = lane >> 4, ii = lane & 15;
  const int m0 = blockIdx.x * 64, n0 = blockIdx.y * 64, bz = blockIdx.z;

  const _Float16* asrc[2];
  const _Float16* bsrc[2];
  int dst8[2];
#pragma unroll
  for (int rep = 0; rep < 2; ++rep) {
    const int idx = tid + 256 * rep;
    dst8[rep] = idx * 8;
    const int j = idx >> 7, c = (idx >> 6) & 1, l = idx & 63;
    const int lq = l >> 4, li = l & 15;
    asrc[rep] = W + (size_t)(m0 + 16 * j + li) * 256 + 32 * c + 8 * lq;
    bsrc[rep] = Bm + ((size_t)(bz * 4096 + n0 + 16 * j + li)) * 256 + 32 * c + 8 * lq;
  }

  f32x4 acc[4] = {};

  half8 ar0 = *(const half8*)asrc[0];
  half8 ar1 = *(const half8*)asrc[1];
  half8 br0 = *(const half8*)bsrc[0];
  half8 br1 = *(const half8*)bsrc[1];
  *(half8*)(a_lds[0] + dst8[0]) = ar0;
  *(half8*)(a_lds[0] + dst8[1]) = ar1;
  *(half8*)(b_lds[0] + dst8[0]) = br0;
  *(half8*)(b_lds[0] + dst8[1]) = br1;
  __syncthreads();

  for (int it = 0; it < 4; ++it) {
    const int cur = it & 1;
    if (it < 3) {
      const int ko = (it + 1) * 64;
      ar0 = *(const half8*)(asrc[0] + ko);
      ar1 = *(const half8*)(asrc[1] + ko);
      br0 = *(const half8*)(bsrc[0] + ko);
      br1 = *(const half8*)(bsrc[1] + ko);
    }
    half8 ah0 = *(const half8*)(a_lds[cur] + ((wv * 2 + 0) * 64 + lane) * 8);
    half8 ah1 = *(const half8*)(a_lds[cur] + ((wv * 2 + 1) * 64 + lane) * 8);
#pragma unroll
    for (int t = 0; t < 4; ++t) {
      half8 b0 = *(const half8*)(b_lds[cur] + ((t * 2 + 0) * 64 + lane) * 8);
      half8 b1 = *(const half8*)(b_lds[cur] + ((t * 2 + 1) * 64 + lane) * 8);
      acc[t] = mfma16(ah0, b0, acc[t]);
      acc[t] = mfma16(ah1, b1, acc[t]);
    }
    if (it < 3) {
      _Float16* an = a_lds[cur ^ 1];
      _Float16* bn = b_lds[cur ^ 1];
      *(half8*)(an + dst8[0]) = ar0;
      *(half8*)(an + dst8[1]) = ar1;
      *(half8*)(bn + dst8[0]) = br0;
      *(half8*)(bn + dst8[1]) = br1;
    }
    __syncthreads();
  }

  const int och0 = m0 + 16 * wv + 4 * qq;
  if (m0 < 512) {
    const float sc = (m0 < 256) ? CSCALE : 1.0f;
#pragma unroll
    for (int t = 0; t < 4; ++t) {
      const int n = n0 + 16 * t + ii;
      unsigned short hh[4];
#pragma unroll
      for (int r = 0; r < 4; ++r) {
        hh[r] = h_bits((_Float16)((acc[t][r] + bias[och0 + r]) * sc));
      }
      int2v u;
      u[0] = hh[0] | (hh[1] << 16);
      u[1] = hh[2] | (hh[3] << 16);
      *(int2v*)(qkT + ((size_t)(bz * 4096 + n)) * 512 + och0) = u;
    }
  } else {
#pragma unroll
    for (int t = 0; t < 4; ++t) {
#pragma unroll
      for (int r = 0; r < 4; ++r) {
        const int och = och0 + r;
        const int d = och - 512;
        const int hd_ = d & 31, head = d >> 5;
        const int n = n0 + 16 * t + ii;
        v_t[((size_t)((bz * 8 + head) * 32 + hd_)) * 4096 + n] =
            (_Float16)((acc[t][r] + bias[och]) * VSCALE);
      }
    }
  }
}

// ---------------------------------------------------------------------------
// 4) Flash attention v6 (R9, best measured): dual-Q, split-K x4 (1024 keys,
//    16 iters of 64), 64-key frag-order LDS tiles, 100% occupancy.
// ---------------------------------------------------------------------------
__global__ __launch_bounds__(256, 8) void attn_kernel(
    const _Float16* __restrict__ qkT, const _Float16* __restrict__ v_t,
    _Float16* __restrict__ opart, float* __restrict__ lpart) {
  __shared__ _Float16 k_lds[2][2048];
  __shared__ _Float16 v_lds[2][2048];
  const int tid = threadIdx.x, lane = tid & 63, wv = tid >> 6;
  const int qq = lane >> 4, ii = lane & 15;
  const int bh = blockIdx.y, b = bh >> 3, h = bh & 7;
  const int n0 = blockIdx.x * 128;
  const int part = blockIdx.z;
  const int key0 = part * 1024;

  const _Float16* qbase =
      qkT + ((size_t)(b * 4096 + n0 + 32 * wv + ii)) * 512 + h * 32 + 8 * qq;
  half8 qf0 = *(const half8*)qbase;
  half8 qf1 = *(const half8*)(qbase + (size_t)16 * 512);

  const int f = tid >> 6, l = tid & 63;
  const int fq = l >> 4, fi = l & 15;
  const int u0 = f >> 1, hf = f & 1;
  const int g = 32 * u0 + 4 * hf + 8 * (fi >> 2) + (fi & 3);  // permuted key
  const _Float16* ksrc =
      qkT + ((size_t)(b * 4096 + key0 + g)) * 512 + 256 + h * 32 + 8 * fq;
  const _Float16* vsrc =
      v_t + ((size_t)(bh * 32 + 16 * hf + fi)) * 4096 + key0 + 32 * u0 + 8 * fq;
  const int dst8 = tid * 8;

  half8 ones8;
#pragma unroll
  for (int j = 0; j < 8; ++j) ones8[j] = (_Float16)1.0f;

  f32x4 o00 = {}, o10 = {}, o01 = {}, o11 = {}, accl0 = {}, accl1 = {};

  half8 kr = *(const half8*)ksrc;
  half8 vr = *(const half8*)vsrc;
  *(half8*)(k_lds[0] + dst8) = kr;
  *(half8*)(v_lds[0] + dst8) = vr;
  __syncthreads();

  for (int kb = 0; kb < 16; ++kb) {
    const int cur = kb & 1;
    if (kb < 15) {
      kr = *(const half8*)(ksrc + (size_t)(kb + 1) * 64 * 512);
      vr = *(const half8*)(vsrc + (size_t)(kb + 1) * 64);
    }
    const _Float16* kbase = k_lds[cur];
    const _Float16* vbase = v_lds[cur];

#pragma unroll
    for (int u = 0; u < 2; ++u) {
      half8 kfa = *(const half8*)(kbase + u * 1024 + lane * 8);
      half8 kfb = *(const half8*)(kbase + u * 1024 + 512 + lane * 8);
      f32x4 z = {};
      f32x4 sa0 = mfma16(kfa, qf0, z);
      f32x4 sb0 = mfma16(kfb, qf0, z);
      f32x4 sa1 = mfma16(kfa, qf1, z);
      f32x4 sb1 = mfma16(kfb, qf1, z);
      int4v p0, p1;
      p0[0] = h2_bits(__builtin_amdgcn_cvt_pkrtz(EXP2(sa0[0]), EXP2(sa0[1])));
      p0[1] = h2_bits(__builtin_amdgcn_cvt_pkrtz(EXP2(sa0[2]), EXP2(sa0[3])));
      p0[2] = h2_bits(__builtin_amdgcn_cvt_pkrtz(EXP2(sb0[0]), EXP2(sb0[1])));
      p0[3] = h2_bits(__builtin_amdgcn_cvt_pkrtz(EXP2(sb0[2]), EXP2(sb0[3])));
      p1[0] = h2_bits(__builtin_amdgcn_cvt_pkrtz(EXP2(sa1[0]), EXP2(sa1[1])));
      p1[1] = h2_bits(__builtin_amdgcn_cvt_pkrtz(EXP2(sa1[2]), EXP2(sa1[3])));
      p1[2] = h2_bits(__builtin_amdgcn_cvt_pkrtz(EXP2(sb1[0]), EXP2(sb1[1])));
      p1[3] = h2_bits(__builtin_amdgcn_cvt_pkrtz(EXP2(sb1[2]), EXP2(sb1[3])));
      half8 pt0 = __builtin_bit_cast(half8, p0);
      half8 pt1 = __builtin_bit_cast(half8, p1);
      half8 vf0 = *(const half8*)(vbase + u * 1024 + lane * 8);
      half8 vf1 = *(const half8*)(vbase + u * 1024 + 512 + lane * 8);
      o00 = mfma16(vf0, pt0, o00);
      o10 = mfma16(vf1, pt0, o10);
      accl0 = mfma16(ones8, pt0, accl0);
      o01 = mfma16(vf0, pt1, o01);
      o11 = mfma16(vf1, pt1, o11);
      accl1 = mfma16(ones8, pt1, accl1);
    }

    if (kb < 15) {
      *(half8*)(k_lds[cur ^ 1] + dst8) = kr;
      *(half8*)(v_lds[cur ^ 1] + dst8) = vr;
    }
    __syncthreads();
  }

  // epilogue: fp16 unnormalized O' partials (V pre-scaled 2^-10), fp32 l.
#pragma unroll
  for (int hfq = 0; hfq < 2; ++hfq) {
    const f32x4 oa = hfq ? o01 : o00;   // d = 4qq+r
    const f32x4 ob = hfq ? o11 : o10;   // d = 16+4qq+r
    const int q = n0 + 32 * wv + 16 * hfq + ii;
    _Float16* base =
        opart + ((size_t)((part * 2 + b) * 4096 + q)) * 256 + h * 32;
    unsigned short hh[4];
    int2v ua;
#pragma unroll
    for (int r = 0; r < 4; ++r) hh[r] = h_bits((_Float16)oa[r]);
    ua[0] = hh[0] | (hh[1] << 16); ua[1] = hh[2] | (hh[3] << 16);
    *(int2v*)(base + 4 * qq) = ua;
#pragma unroll
    for (int r = 0; r < 4; ++r) hh[r] = h_bits((_Float16)ob[r]);
    ua[0] = hh[0] | (hh[1] << 16); ua[1] = hh[2] | (hh[3] << 16);
    *(int2v*)(base + 16 + 4 * qq) = ua;
    if (qq == 0) {
      lpart[((size_t)((part * 2 + b) * 4096 + q)) * 8 + h] =
          hfq ? accl1[0] : accl0[0];
    }
  }
}

// ---------------------------------------------------------------------------
// 5) lsum: linv[(b*4096+q)*8+h] = 2^10 / sum_p lpart  (65536 elements).
// ---------------------------------------------------------------------------
__global__ __launch_bounds__(256) void lsum(const float* __restrict__ lpart,
                                            float* __restrict__ linv) {
  const int i = blockIdx.x * 256 + threadIdx.x;  // (b*4096+q)*8+h, b folded
  float L = lpart[i] + lpart[i + 65536] + lpart[i + 131072] + lpart[i + 196608];
  linv[i] = VUNSC / L;
}

// ---------------------------------------------------------------------------
// 6) proj GEMM with fused softmax normalization: B-staging sums the 4 fp16
//    O' partials and multiplies by linv[q][h] (h = channel>>5, uniform per
//    staged half8).  out fp32 [b][c][n] + bias.
// ---------------------------------------------------------------------------
__global__ __launch_bounds__(256) void gemm_proj(
    const _Float16* __restrict__ W, const _Float16* __restrict__ opart,
    const float* __restrict__ linv, const float* __restrict__ bias,
    float* __restrict__ outp) {
  __shared__ _Float16 a_lds[2][4096];
  __shared__ _Float16 b_lds[2][4096];
  const int tid = threadIdx.x, lane = tid & 63, wv = tid >> 6;
  const int qq = lane >> 4, ii = lane & 15;
  const int m0 = blockIdx.x * 64, n0 = blockIdx.y * 64, bz = blockIdx.z;
  const size_t PSTR = (size_t)2 * 4096 * 256;  // opart part stride (elements)

  const _Float16* asrc[2];
  const _Float16* bsrc[2];
  int dst8[2], li_idx[2], cch[2];
#pragma unroll
  for (int rep = 0; rep < 2; ++rep) {
    const int idx = tid + 256 * rep;
    dst8[rep] = idx * 8;
    const int j = idx >> 7, c = (idx >> 6) & 1, l = idx & 63;
    const int lq = l >> 4, li = l & 15;
    const int q = n0 + 16 * j + li;
    asrc[rep] = W + (size_t)(m0 + 16 * j + li) * 256 + 32 * c + 8 * lq;
    bsrc[rep] = opart + ((size_t)(bz * 4096 + q)) * 256 + 32 * c + 8 * lq;
    li_idx[rep] = (bz * 4096 + q) * 8 + c;  // + 2*it at use
    cch[rep] = c;
  }

  f32x4 acc[4] = {};

  auto stage_b = [&](int rep, int ko, int it) -> half8 {
    const _Float16* p = bsrc[rep] + ko;
    half8 s0 = *(const half8*)p;
    half8 s1 = *(const half8*)(p + PSTR);
    half8 s2 = *(const half8*)(p + 2 * PSTR);
    half8 s3 = *(const half8*)(p + 3 * PSTR);
    half8 s = (s0 + s1) + (s2 + s3);
    const _Float16 invh = (_Float16)linv[li_idx[rep] + 2 * it];
#pragma unroll
    for (int j = 0; j < 8; ++j) s[j] *= invh;
    return s;
  };

  half8 ar0 = *(const half8*)asrc[0];
  half8 ar1 = *(const half8*)asrc[1];
  half8 br0 = stage_b(0, 0, 0);
  half8 br1 = stage_b(1, 0, 0);
  *(half8*)(a_lds[0] + dst8[0]) = ar0;
  *(half8*)(a_lds[0] + dst8[1]) = ar1;
  *(half8*)(b_lds[0] + dst8[0]) = br0;
  *(half8*)(b_lds[0] + dst8[1]) = br1;
  __syncthreads();

  for (int it = 0; it < 4; ++it) {
    const int cur = it & 1;
    if (it < 3) {
      const int ko = (it + 1) * 64;
      ar0 = *(const half8*)(asrc[0] + ko);
      ar1 = *(const half8*)(asrc[1] + ko);
      br0 = stage_b(0, ko, it + 1);
      br1 = stage_b(1, ko, it + 1);
    }
    half8 ah0 = *(const half8*)(a_lds[cur] + ((wv * 2 + 0) * 64 + lane) * 8);
    half8 ah1 = *(const half8*)(a_lds[cur] + ((wv * 2 + 1) * 64 + lane) * 8);
#pragma unroll
    for (int t = 0; t < 4; ++t) {
      half8 b0 = *(const half8*)(b_lds[cur] + ((t * 2 + 0) * 64 + lane) * 8);
      half8 b1 = *(const half8*)(b_lds[cur] + ((t * 2 + 1) * 64 + lane) * 8);
      acc[t] = mfma16(ah0, b0, acc[t]);
      acc[t] = mfma16(ah1, b1, acc[t]);
    }
    if (it < 3) {
      _Float16* an = a_lds[cur ^ 1];
      _Float16* bn = b_lds[cur ^ 1];
      *(half8*)(an + dst8[0]) = ar0;
      *(half8*)(an + dst8[1]) = ar1;
      *(half8*)(bn + dst8[0]) = br0;
      *(half8*)(bn + dst8[1]) = br1;
    }
    __syncthreads();
  }

  const int och0 = m0 + 16 * wv + 4 * qq;
#pragma unroll
  for (int t = 0; t < 4; ++t) {
#pragma unroll
    for (int r = 0; r < 4; ++r) {
      const int och = och0 + r;
      const int n = n0 + 16 * t + ii;
      outp[((size_t)(bz * 256 + och)) * 4096 + n] = acc[t][r] + bias[och];
    }
  }
}

// ---------------------------------------------------------------------------
extern "C" void kernel_launch(void* const* d_in, const int* in_sizes, int n_in,
                              void* d_out, int out_size, void* d_ws, size_t ws_size,
                              hipStream_t stream) {
  const float* x     = (const float*)d_in[0];
  const float* gnw   = (const float*)d_in[1];
  const float* gnb   = (const float*)d_in[2];
  const float* wqkv  = (const float*)d_in[3];
  const float* bqkv  = (const float*)d_in[4];
  const float* wproj = (const float*)d_in[5];
  const float* bproj = (const float*)d_in[6];
  float* out = (float*)d_out;

  char* ws = (char*)d_ws;
  size_t off = 0;
  auto alloc = [&](size_t bytes) -> char* {
    char* p = ws + off;
    off += (bytes + 255) & ~(size_t)255;
    return p;
  };
  float*    stats  = (float*)alloc(128);
  _Float16* hn     = (_Float16*)alloc((size_t)2 * 4096 * 256 * 2);
  _Float16* wq_h   = (_Float16*)alloc((size_t)768 * 256 * 2);
  _Float16* wp_h   = (_Float16*)alloc((size_t)256 * 256 * 2);
  _Float16* qkT    = (_Float16*)alloc((size_t)2 * 4096 * 512 * 2);
  _Float16* v_t    = (_Float16*)alloc((size_t)16 * 32 * 4096 * 2);
  _Float16* opart  = (_Float16*)alloc((size_t)8 * 4096 * 256 * 2);
  float*    lpart  = (float*)alloc((size_t)8 * 4096 * 8 * 4);
  float*    linv   = (float*)alloc((size_t)2 * 4096 * 8 * 4);
  if (off > ws_size) return;

  (void)hipMemsetAsync(stats, 0, 256, stream);
  prep<<<1536, 256, 0, stream>>>(x, stats, wqkv, wproj, wq_h, wp_h);
  gn_apply<<<dim3(64, 4, 2), 256, 0, stream>>>(x, gnw, gnb, stats, hn);
  gemm_qkv<<<dim3(12, 64, 2), 256, 0, stream>>>(wq_h, hn, bqkv, qkT, v_t);
  attn_kernel<<<dim3(32, 16, 4), 256, 0, stream>>>(qkT, v_t, opart, lpart);
  lsum<<<256, 256, 0, stream>>>(lpart, linv);
  gemm_proj<<<dim3(4, 64, 2), 256, 0, stream>>>(wp_h, opart, linv, bproj, out);
}

// Round 13
// 163.814 us; speedup vs baseline: 1.1331x; 1.0536x over previous
//
#include <hip/hip_runtime.h>

// ---------------------------------------------------------------------------
// MultiHeadSelfAttention: GroupNorm(8,256) -> qkv 1x1 -> 8-head attn (N=4096,
// hd=32) -> proj 1x1.  B=2, C=256, H=W=64.
// R13 = recombination of per-stage measured bests:
//   - prep: fused GN-stats + W fp32->fp16 cast (one dispatch).
//   - gemms: plain fp16 MFMA, fp16 W from prep (fp32 inline staging was -9us).
//   - attn v6 (best measured 56.4us): dual-Q waves, split-K x4 (1024 keys),
//     64-key frag-order LDS tiles (0 conflicts), S^T operand-swap keeps P in
//     registers, K=32 PV via permuted K staging, 100% occupancy.
//   - plain 4-part streaming combine (fused-norm proj regressed R12).
//   - Fixed ~47us harness workspace-poison floor is not addressable.
// ---------------------------------------------------------------------------

typedef _Float16 half8 __attribute__((ext_vector_type(8)));
typedef __fp16   fp16x2 __attribute__((ext_vector_type(2)));  // pkrtz return type
typedef float    f32x4 __attribute__((ext_vector_type(4)));
typedef int      int2v __attribute__((ext_vector_type(2)));
typedef int      int4v __attribute__((ext_vector_type(4)));

__device__ __forceinline__ f32x4 mfma16(half8 a, half8 b, f32x4 c) {
  return __builtin_amdgcn_mfma_f32_16x16x32_f16(a, b, c, 0, 0, 0);
}

#if __has_builtin(__builtin_amdgcn_exp2f)
#define EXP2(x) __builtin_amdgcn_exp2f(x)
#else
#define EXP2(x) exp2f(x)
#endif

__device__ __forceinline__ unsigned short h_bits(_Float16 h) {
  return __builtin_bit_cast(unsigned short, h);
}
__device__ __forceinline__ int h2_bits(fp16x2 h) {
  return __builtin_bit_cast(int, h);
}

constexpr float CSCALE = (float)(1.4426950408889634 / 5.656854249492381); // log2(e)/sqrt(32)
constexpr float VSCALE = 0.0009765625f;   // 2^-10: bounds unnormalized O for fp16
constexpr float VUNSC  = 1024.0f;

// ---------------------------------------------------------------------------
// 1) prep: GroupNorm stats (blocks 0..511) + weight cast (blocks 512..1535).
// ---------------------------------------------------------------------------
__global__ __launch_bounds__(256) void prep(const float* __restrict__ x,
                                            float* __restrict__ stats,
                                            const float* __restrict__ wq,
                                            const float* __restrict__ wp,
                                            _Float16* __restrict__ wqh,
                                            _Float16* __restrict__ wph) {
  const int tid = threadIdx.x;
  if (blockIdx.x < 512) {
    const int bg = blockIdx.x >> 5, ch = blockIdx.x & 31;
    const float* p = x + (size_t)bg * 131072 + (size_t)ch * 4096;
    float s = 0.f, ss = 0.f;
#pragma unroll
    for (int j = 0; j < 4; ++j) {
      f32x4 v = *(const f32x4*)(p + j * 1024 + tid * 4);
#pragma unroll
      for (int k = 0; k < 4; ++k) { s += v[k]; ss += v[k] * v[k]; }
    }
#pragma unroll
    for (int m = 1; m <= 32; m <<= 1) { s += __shfl_xor(s, m); ss += __shfl_xor(ss, m); }
    __shared__ float red[8];
    const int wv = tid >> 6;
    if ((tid & 63) == 0) { red[wv * 2] = s; red[wv * 2 + 1] = ss; }
    __syncthreads();
    if (tid == 0) {
      float S = red[0] + red[2] + red[4] + red[6];
      float SS = red[1] + red[3] + red[5] + red[7];
      atomicAdd(&stats[bg * 2], S);
      atomicAdd(&stats[bg * 2 + 1], SS);
    }
  } else {
    const int idx = (blockIdx.x - 512) * 256 + tid;
    if (idx < 196608) {
      wqh[idx] = (_Float16)wq[idx];
    } else {
      wph[idx - 196608] = (_Float16)wp[idx - 196608];
    }
  }
}

// ---------------------------------------------------------------------------
// 2) GroupNorm apply + transpose: x[b][c][n] -> hn[b][n][c] (fp16).
// ---------------------------------------------------------------------------
__global__ __launch_bounds__(256) void gn_apply(const float* __restrict__ x,
                                                const float* __restrict__ gw,
                                                const float* __restrict__ gb,
                                                const float* __restrict__ stats,
                                                _Float16* __restrict__ hn) {
  __shared__ float tile[64 * 65];
  const int tid = threadIdx.x;
  const int a = tid & 15;
  const int row16 = tid >> 4;
  const int b = blockIdx.z, c0 = blockIdx.y * 64, n0 = blockIdx.x * 64;
#pragma unroll
  for (int m = 0; m < 4; ++m) {
    const int cl = row16 + 16 * m;
    const int c = c0 + cl;
    const int g = c >> 5;
    const float s = stats[(b * 8 + g) * 2];
    const float ss = stats[(b * 8 + g) * 2 + 1];
    const float mean = s * (1.f / 131072.f);
    const float var = ss * (1.f / 131072.f) - mean * mean;
    const float rstd = rsqrtf(var + 1e-5f);
    const float ga = gw[c] * rstd;
    const float be = gb[c] - mean * ga;
    f32x4 xv = *(const f32x4*)(x + ((size_t)(b * 256 + c)) * 4096 + n0 + a * 4);
#pragma unroll
    for (int j = 0; j < 4; ++j) tile[cl * 65 + a * 4 + j] = xv[j] * ga + be;
  }
  __syncthreads();
#pragma unroll
  for (int m = 0; m < 4; ++m) {
    const int nl = row16 + 16 * m;
    const int cb = a * 4;
    int2v uh;
    unsigned short hh[4];
#pragma unroll
    for (int j = 0; j < 4; ++j) {
      hh[j] = h_bits((_Float16)tile[(cb + j) * 65 + nl]);
    }
    uh[0] = hh[0] | (hh[1] << 16); uh[1] = hh[2] | (hh[3] << 16);
    size_t off = ((size_t)(b * 4096 + n0 + nl)) * 256 + c0 + cb;
    *(int2v*)(hn + off) = uh;
  }
}

// ---------------------------------------------------------------------------
// 3) fp16 GEMM: out[M][4096] = W[M][256] @ Bm^T  (Bm is [b][n][256] fp16).
//    64x64 tile, BK=64, frag-order LDS, register-prefetch 1-barrier K-loop.
//    MODE 0 (QKV, M=768): q*CSCALE,k -> qkT[b][n][512]; v*2^-10 -> v_t.
//    MODE 1 (proj, M=256): fp32 out[b][c][n] + bias.
// ---------------------------------------------------------------------------
template <int MODE>
__global__ __launch_bounds__(256) void gemm_f16(
    const _Float16* __restrict__ W, const _Float16* __restrict__ Bm,
    const float* __restrict__ bias,
    _Float16* __restrict__ qkT, _Float16* __restrict__ v_t,
    float* __restrict__ outp) {
  __shared__ _Float16 a_lds[2][4096];
  __shared__ _Float16 b_lds[2][4096];
  const int tid = threadIdx.x, lane = tid & 63, wv = tid >> 6;
  const int qq = lane >> 4, ii = lane & 15;
  const int m0 = blockIdx.x * 64, n0 = blockIdx.y * 64, bz = blockIdx.z;

  const _Float16* asrc[2];
  const _Float16* bsrc[2];
  int dst8[2];
#pragma unroll
  for (int rep = 0; rep < 2; ++rep) {
    const int idx = tid + 256 * rep;
    dst8[rep] = idx * 8;
    const int j = idx >> 7, c = (idx >> 6) & 1, l = idx & 63;
    const int lq = l >> 4, li = l & 15;
    asrc[rep] = W + (size_t)(m0 + 16 * j + li) * 256 + 32 * c + 8 * lq;
    bsrc[rep] = Bm + ((size_t)(bz * 4096 + n0 + 16 * j + li)) * 256 + 32 * c + 8 * lq;
  }

  f32x4 acc[4] = {};

  half8 ar0 = *(const half8*)asrc[0];
  half8 ar1 = *(const half8*)asrc[1];
  half8 br0 = *(const half8*)bsrc[0];
  half8 br1 = *(const half8*)bsrc[1];
  *(half8*)(a_lds[0] + dst8[0]) = ar0;
  *(half8*)(a_lds[0] + dst8[1]) = ar1;
  *(half8*)(b_lds[0] + dst8[0]) = br0;
  *(half8*)(b_lds[0] + dst8[1]) = br1;
  __syncthreads();

  for (int it = 0; it < 4; ++it) {
    const int cur = it & 1;
    if (it < 3) {
      const int ko = (it + 1) * 64;
      ar0 = *(const half8*)(asrc[0] + ko);
      ar1 = *(const half8*)(asrc[1] + ko);
      br0 = *(const half8*)(bsrc[0] + ko);
      br1 = *(const half8*)(bsrc[1] + ko);
    }
    half8 ah0 = *(const half8*)(a_lds[cur] + ((wv * 2 + 0) * 64 + lane) * 8);
    half8 ah1 = *(const half8*)(a_lds[cur] + ((wv * 2 + 1) * 64 + lane) * 8);
#pragma unroll
    for (int t = 0; t < 4; ++t) {
      half8 b0 = *(const half8*)(b_lds[cur] + ((t * 2 + 0) * 64 + lane) * 8);
      half8 b1 = *(const half8*)(b_lds[cur] + ((t * 2 + 1) * 64 + lane) * 8);
      acc[t] = mfma16(ah0, b0, acc[t]);
      acc[t] = mfma16(ah1, b1, acc[t]);
    }
    if (it < 3) {
      _Float16* an = a_lds[cur ^ 1];
      _Float16* bn = b_lds[cur ^ 1];
      *(half8*)(an + dst8[0]) = ar0;
      *(half8*)(an + dst8[1]) = ar1;
      *(half8*)(bn + dst8[0]) = br0;
      *(half8*)(bn + dst8[1]) = br1;
    }
    __syncthreads();
  }

  const int och0 = m0 + 16 * wv + 4 * qq;
  if (MODE == 0) {
    if (m0 < 512) {
      const float sc = (m0 < 256) ? CSCALE : 1.0f;
#pragma unroll
      for (int t = 0; t < 4; ++t) {
        const int n = n0 + 16 * t + ii;
        unsigned short hh[4];
#pragma unroll
        for (int r = 0; r < 4; ++r) {
          hh[r] = h_bits((_Float16)((acc[t][r] + bias[och0 + r]) * sc));
        }
        int2v u;
        u[0] = hh[0] | (hh[1] << 16);
        u[1] = hh[2] | (hh[3] << 16);
        *(int2v*)(qkT + ((size_t)(bz * 4096 + n)) * 512 + och0) = u;
      }
    } else {
#pragma unroll
      for (int t = 0; t < 4; ++t) {
#pragma unroll
        for (int r = 0; r < 4; ++r) {
          const int och = och0 + r;
          const int d = och - 512;
          const int hd_ = d & 31, head = d >> 5;
          const int n = n0 + 16 * t + ii;
          v_t[((size_t)((bz * 8 + head) * 32 + hd_)) * 4096 + n] =
              (_Float16)((acc[t][r] + bias[och]) * VSCALE);
        }
      }
    }
  } else {
#pragma unroll
    for (int t = 0; t < 4; ++t) {
#pragma unroll
      for (int r = 0; r < 4; ++r) {
        const int och = och0 + r;
        const int n = n0 + 16 * t + ii;
        outp[((size_t)(bz * 256 + och)) * 4096 + n] = acc[t][r] + bias[och];
      }
    }
  }
}

// ---------------------------------------------------------------------------
// 4) Flash attention v6 (best measured): dual-Q, split-K x4 (1024 keys,
//    16 iters of 64), 64-key frag-order LDS tiles, 100% occupancy.
// ---------------------------------------------------------------------------
__global__ __launch_bounds__(256, 8) void attn_kernel(
    const _Float16* __restrict__ qkT, const _Float16* __restrict__ v_t,
    _Float16* __restrict__ opart, float* __restrict__ lpart) {
  __shared__ _Float16 k_lds[2][2048];
  __shared__ _Float16 v_lds[2][2048];
  const int tid = threadIdx.x, lane = tid & 63, wv = tid >> 6;
  const int qq = lane >> 4, ii = lane & 15;
  const int bh = blockIdx.y, b = bh >> 3, h = bh & 7;
  const int n0 = blockIdx.x * 128;
  const int part = blockIdx.z;
  const int key0 = part * 1024;

  const _Float16* qbase =
      qkT + ((size_t)(b * 4096 + n0 + 32 * wv + ii)) * 512 + h * 32 + 8 * qq;
  half8 qf0 = *(const half8*)qbase;
  half8 qf1 = *(const half8*)(qbase + (size_t)16 * 512);

  const int f = tid >> 6, l = tid & 63;
  const int fq = l >> 4, fi = l & 15;
  const int u0 = f >> 1, hf = f & 1;
  const int g = 32 * u0 + 4 * hf + 8 * (fi >> 2) + (fi & 3);  // permuted key
  const _Float16* ksrc =
      qkT + ((size_t)(b * 4096 + key0 + g)) * 512 + 256 + h * 32 + 8 * fq;
  const _Float16* vsrc =
      v_t + ((size_t)(bh * 32 + 16 * hf + fi)) * 4096 + key0 + 32 * u0 + 8 * fq;
  const int dst8 = tid * 8;

  half8 ones8;
#pragma unroll
  for (int j = 0; j < 8; ++j) ones8[j] = (_Float16)1.0f;

  f32x4 o00 = {}, o10 = {}, o01 = {}, o11 = {}, accl0 = {}, accl1 = {};

  half8 kr = *(const half8*)ksrc;
  half8 vr = *(const half8*)vsrc;
  *(half8*)(k_lds[0] + dst8) = kr;
  *(half8*)(v_lds[0] + dst8) = vr;
  __syncthreads();

  for (int kb = 0; kb < 16; ++kb) {
    const int cur = kb & 1;
    if (kb < 15) {
      kr = *(const half8*)(ksrc + (size_t)(kb + 1) * 64 * 512);
      vr = *(const half8*)(vsrc + (size_t)(kb + 1) * 64);
    }
    const _Float16* kbase = k_lds[cur];
    const _Float16* vbase = v_lds[cur];

#pragma unroll
    for (int u = 0; u < 2; ++u) {
      half8 kfa = *(const half8*)(kbase + u * 1024 + lane * 8);
      half8 kfb = *(const half8*)(kbase + u * 1024 + 512 + lane * 8);
      f32x4 z = {};
      f32x4 sa0 = mfma16(kfa, qf0, z);
      f32x4 sb0 = mfma16(kfb, qf0, z);
      f32x4 sa1 = mfma16(kfa, qf1, z);
      f32x4 sb1 = mfma16(kfb, qf1, z);
      int4v p0, p1;
      p0[0] = h2_bits(__builtin_amdgcn_cvt_pkrtz(EXP2(sa0[0]), EXP2(sa0[1])));
      p0[1] = h2_bits(__builtin_amdgcn_cvt_pkrtz(EXP2(sa0[2]), EXP2(sa0[3])));
      p0[2] = h2_bits(__builtin_amdgcn_cvt_pkrtz(EXP2(sb0[0]), EXP2(sb0[1])));
      p0[3] = h2_bits(__builtin_amdgcn_cvt_pkrtz(EXP2(sb0[2]), EXP2(sb0[3])));
      p1[0] = h2_bits(__builtin_amdgcn_cvt_pkrtz(EXP2(sa1[0]), EXP2(sa1[1])));
      p1[1] = h2_bits(__builtin_amdgcn_cvt_pkrtz(EXP2(sa1[2]), EXP2(sa1[3])));
      p1[2] = h2_bits(__builtin_amdgcn_cvt_pkrtz(EXP2(sb1[0]), EXP2(sb1[1])));
      p1[3] = h2_bits(__builtin_amdgcn_cvt_pkrtz(EXP2(sb1[2]), EXP2(sb1[3])));
      half8 pt0 = __builtin_bit_cast(half8, p0);
      half8 pt1 = __builtin_bit_cast(half8, p1);
      half8 vf0 = *(const half8*)(vbase + u * 1024 + lane * 8);
      half8 vf1 = *(const half8*)(vbase + u * 1024 + 512 + lane * 8);
      o00 = mfma16(vf0, pt0, o00);
      o10 = mfma16(vf1, pt0, o10);
      accl0 = mfma16(ones8, pt0, accl0);
      o01 = mfma16(vf0, pt1, o01);
      o11 = mfma16(vf1, pt1, o11);
      accl1 = mfma16(ones8, pt1, accl1);
    }

    if (kb < 15) {
      *(half8*)(k_lds[cur ^ 1] + dst8) = kr;
      *(half8*)(v_lds[cur ^ 1] + dst8) = vr;
    }
    __syncthreads();
  }

  // epilogue: fp16 unnormalized O' partials (V pre-scaled 2^-10), fp32 l.
#pragma unroll
  for (int hfq = 0; hfq < 2; ++hfq) {
    const f32x4 oa = hfq ? o01 : o00;   // d = 4qq+r
    const f32x4 ob = hfq ? o11 : o10;   // d = 16+4qq+r
    const int q = n0 + 32 * wv + 16 * hfq + ii;
    _Float16* base =
        opart + ((size_t)((part * 2 + b) * 4096 + q)) * 256 + h * 32;
    unsigned short hh[4];
    int2v ua;
#pragma unroll
    for (int r = 0; r < 4; ++r) hh[r] = h_bits((_Float16)oa[r]);
    ua[0] = hh[0] | (hh[1] << 16); ua[1] = hh[2] | (hh[3] << 16);
    *(int2v*)(base + 4 * qq) = ua;
#pragma unroll
    for (int r = 0; r < 4; ++r) hh[r] = h_bits((_Float16)ob[r]);
    ua[0] = hh[0] | (hh[1] << 16); ua[1] = hh[2] | (hh[3] << 16);
    *(int2v*)(base + 16 + 4 * qq) = ua;
    if (qq == 0) {
      lpart[((size_t)((part * 2 + b) * 4096 + q)) * 8 + h] =
          hfq ? accl1[0] : accl0[0];
    }
  }
}

// ---------------------------------------------------------------------------
// 5) Combine 4 split-K partials: o = 2^10 * sum(O') / sum(l), emit fp16.
// ---------------------------------------------------------------------------
__global__ __launch_bounds__(256) void attn_combine(
    const _Float16* __restrict__ opart, const float* __restrict__ lpart,
    _Float16* __restrict__ o16) {
  const int c = threadIdx.x, hh = c >> 5;
#pragma unroll
  for (int k = 0; k < 4; ++k) {
    const int row = blockIdx.x * 4 + k;          // (b*4096+q)
    const int b = row >> 12, q = row & 4095;
    float O = 0.f, L = 0.f;
#pragma unroll
    for (int p = 0; p < 4; ++p) {
      O += (float)opart[((size_t)((p * 2 + b) * 4096 + q)) * 256 + c];
      L += lpart[((size_t)((p * 2 + b) * 4096 + q)) * 8 + hh];
    }
    o16[(size_t)row * 256 + c] = (_Float16)(O * (VUNSC / L));
  }
}

// ---------------------------------------------------------------------------
extern "C" void kernel_launch(void* const* d_in, const int* in_sizes, int n_in,
                              void* d_out, int out_size, void* d_ws, size_t ws_size,
                              hipStream_t stream) {
  const float* x     = (const float*)d_in[0];
  const float* gnw   = (const float*)d_in[1];
  const float* gnb   = (const float*)d_in[2];
  const float* wqkv  = (const float*)d_in[3];
  const float* bqkv  = (const float*)d_in[4];
  const float* wproj = (const float*)d_in[5];
  const float* bproj = (const float*)d_in[6];
  float* out = (float*)d_out;

  char* ws = (char*)d_ws;
  size_t off = 0;
  auto alloc = [&](size_t bytes) -> char* {
    char* p = ws + off;
    off += (bytes + 255) & ~(size_t)255;
    return p;
  };
  float*    stats  = (float*)alloc(128);
  _Float16* hn     = (_Float16*)alloc((size_t)2 * 4096 * 256 * 2);
  _Float16* wq_h   = (_Float16*)alloc((size_t)768 * 256 * 2);
  _Float16* wp_h   = (_Float16*)alloc((size_t)256 * 256 * 2);
  _Float16* qkT    = (_Float16*)alloc((size_t)2 * 4096 * 512 * 2);
  _Float16* v_t    = (_Float16*)alloc((size_t)16 * 32 * 4096 * 2);
  _Float16* opart  = (_Float16*)alloc((size_t)8 * 4096 * 256 * 2);
  float*    lpart  = (float*)alloc((size_t)8 * 4096 * 8 * 4);
  _Float16* o16 = hn;  // hn dead after gemm<0>
  if (off > ws_size) return;

  (void)hipMemsetAsync(stats, 0, 256, stream);
  prep<<<1536, 256, 0, stream>>>(x, stats, wqkv, wproj, wq_h, wp_h);
  gn_apply<<<dim3(64, 4, 2), 256, 0, stream>>>(x, gnw, gnb, stats, hn);
  gemm_f16<0><<<dim3(12, 64, 2), 256, 0, stream>>>(wq_h, hn, bqkv, qkT, v_t,
                                                   nullptr);
  attn_kernel<<<dim3(32, 16, 4), 256, 0, stream>>>(qkT, v_t, opart, lpart);
  attn_combine<<<2048, 256, 0, stream>>>(opart, lpart, o16);
  gemm_f16<1><<<dim3(4, 64, 2), 256, 0, stream>>>(wp_h, o16, bproj, nullptr,
                                                  nullptr, out);
}